// Round 18
// baseline (1823.253 us; speedup 1.0000x reference)
//
#include <hip/hip_runtime.h>
#include <hip/hip_bf16.h>

// Problem constants
#define B_   32
#define T_   48
#define S_   30
#define INF  16
#define H1   128
#define OUTF 64
#define H    3840     // GRU hidden (= GRU input here)
#define G3   11520    // 3*H
#define K_   3840
#define M_   1536     // B_*T_

typedef _Float16 f16x8 __attribute__((ext_vector_type(8)));  // 8 fp16 (4 VGPR)
typedef __attribute__((ext_vector_type(4))) float f32x4;     // MFMA acc

// async global->LDS, 16B per lane; LDS dest must be wave-uniform (HW adds lane*16)
__device__ inline void gl_lds16(const void* g, void* l) {
  __builtin_amdgcn_global_load_lds((const __attribute__((address_space(1))) void*)g,
                                   (__attribute__((address_space(3))) void*)l, 16, 0, 0);
}

// ---------------- kernel 0: zero floats ----------------
__global__ void k_zero(float* __restrict__ p, int n) {
  int i = blockIdx.x * 256 + threadIdx.x;
  if (i < n) p[i] = 0.0f;
}

// ---------------- kernel: [G3][K] fp32 -> single fp16 (used for W_ih AND W_hh) ----------------
__global__ __launch_bounds__(256) void k_cvt_whh(const float* __restrict__ W,
                                                 unsigned short* __restrict__ Wh) {
  size_t i = ((size_t)blockIdx.x * 256 + threadIdx.x) * 8;
  const float4* p = (const float4*)(W + i);
  float4 f0 = p[0], f1 = p[1];
  union { float4 f4; _Float16 h[8]; } ph;
  ph.h[0] = (_Float16)f0.x; ph.h[1] = (_Float16)f0.y;
  ph.h[2] = (_Float16)f0.z; ph.h[3] = (_Float16)f0.w;
  ph.h[4] = (_Float16)f1.x; ph.h[5] = (_Float16)f1.y;
  ph.h[6] = (_Float16)f1.z; ph.h[7] = (_Float16)f1.w;
  *(float4*)(Wh + i) = ph.f4;
}

// ---------------- kernel 1: FC(16->128)+ReLU -> xi single fp16 [T][B][S*128] ----------------
__global__ __launch_bounds__(128) void k_fc_relu(const float* __restrict__ x,
                                                 const float* __restrict__ fc_w,
                                                 const float* __restrict__ fc_b,
                                                 unsigned short* __restrict__ xi_h) {
  int idx = blockIdx.x;              // (b*T_+t)*S_+s
  int s  = idx % S_;
  int bt = idx / S_;
  int t  = bt % T_;
  int b  = bt / T_;
  int hh = threadIdx.x;              // 0..127
  const float* xr = x + (size_t)idx * INF;
  const float* w  = fc_w + (size_t)hh * INF;
  float acc = fc_b[hh];
  #pragma unroll
  for (int i = 0; i < INF; ++i) acc = fmaf(xr[i], w[i], acc);
  acc = fmaxf(acc, 0.0f);
  union { _Float16 f; unsigned short u; } cv;
  cv.f = (_Float16)acc;
  xi_h[((size_t)t * B_ + b) * H + s * H1 + hh] = cv.u;
}

// ---------------- kernel 2: gx = xi @ W_ih^T + b_ih (m97-structure, proven ~275us) ----------------
__global__ __launch_bounds__(256) void k_gemm_f16(const unsigned short* __restrict__ Ahg,
                                                  const unsigned short* __restrict__ Bwh,
                                                  const float* __restrict__ bias,
                                                  float* __restrict__ C) {
  __shared__ __align__(16) char smem[16640];     // Ah:0  Bh:8192 ; epilogue overlay 16640B
  const int tid = threadIdx.x;
  const int NB = G3 / 128;                       // 90, n-fast linear
  const int n0 = (blockIdx.x % NB) * 128;
  const int m0 = (blockIdx.x / NB) * 128;
  const int wave = tid >> 6, lane = tid & 63;
  const int wm = (wave >> 1) * 64, wn = (wave & 1) * 64;
  const int fr = lane & 15, fo = lane >> 4;      // frag row, k-octet

  f32x4 acc[4][4];
  #pragma unroll
  for (int i = 0; i < 4; ++i)
    #pragma unroll
    for (int j = 0; j < 4; ++j) { acc[i][j].x = 0.f; acc[i][j].y = 0.f; acc[i][j].z = 0.f; acc[i][j].w = 0.f; }

  for (int k0 = 0; k0 < K_; k0 += 32) {
    __syncthreads();                             // prev compute done before overwrite
    #pragma unroll
    for (int q = 0; q < 2; ++q) {
      const int i = wave * 2 + q;                // 0..7, wave-uniform
      const int idx = i * 64 + lane;             // 0..511
      const int row = idx >> 2, oct = idx & 3;   // 4 lanes/row: 64B coalesced
      const size_t ga = (size_t)(m0 + row) * K_ + k0 + oct * 8;
      const size_t gb = (size_t)(n0 + row) * K_ + k0 + oct * 8;
      gl_lds16(Ahg + ga, smem + i * 1024);
      gl_lds16(Bwh + gb, smem + 8192 + i * 1024);
    }
    __syncthreads();                             // vmcnt(0) drain -> tiles ready
    f16x8 ah[4];
    #pragma unroll
    for (int mi = 0; mi < 4; ++mi)
      ah[mi] = *(const f16x8*)(smem + (wm + mi * 16 + fr) * 64 + fo * 16);
    #pragma unroll
    for (int ni = 0; ni < 4; ++ni) {
      f16x8 bh = *(const f16x8*)(smem + 8192 + (wn + ni * 16 + fr) * 64 + fo * 16);
      #pragma unroll
      for (int mi = 0; mi < 4; ++mi)
        acc[mi][ni] = __builtin_amdgcn_mfma_f32_16x16x32_f16(ah[mi], bh, acc[mi][ni], 0, 0, 0);
    }
  }
  // epilogue: per-wave LDS transpose -> 256B-contiguous float4 rows (round-1 pattern)
  __syncthreads();                               // all waves done with staged tiles
  float* ep = (float*)(smem) + wave * (16 * 65); // 4160 B/wave, 16640 B total
  #pragma unroll
  for (int mi = 0; mi < 4; ++mi) {
    #pragma unroll
    for (int ni = 0; ni < 4; ++ni) {
      float bc = bias[n0 + wn + ni * 16 + fr];
      #pragma unroll
      for (int r = 0; r < 4; ++r)
        ep[(fo * 4 + r) * 65 + ni * 16 + fr] = acc[mi][ni][r] + bc;
    }
    #pragma unroll
    for (int rr = 0; rr < 4; ++rr) {             // in-wave lgkmcnt ordering suffices
      int lr = rr * 4 + (lane >> 4);             // 0..15
      int lc = (lane & 15) * 4;                  // 0..60
      float4 v = *(float4*)&ep[lr * 65 + lc];
      int row = m0 + wm + mi * 16 + lr;
      *(float4*)(C + (size_t)row * G3 + n0 + wn + lc) = v;   // 16 lanes = 256B/row
    }
  }
}

// ---------------- kernel 3: partial gh via MFMA, single-fp16 h ----------------
// vs round 17: KSP 6 (KSTR 640) -> partials 11.8->8.85MB/step; grid (6,45)=270 >= 256 CUs.
// In-flight W bytes per CU (8 waves x 4KB) still >> latency-BW product; W stream stays
// at its ~5.5 TB/s L3-service floor while the partial round-trip shrinks.
#define KSP  6
#define KSTR 640
__global__ __launch_bounds__(256, 4) void k_gh_direct(const unsigned short* __restrict__ hh_g,
                                                      const unsigned short* __restrict__ Wh_g,
                                                      float* __restrict__ part) {
  // rows padded 640->648 ushorts (1296B stride, 16B-aligned, 8-elem aligned)
  __shared__ unsigned short Hh[32][648];
  const int tid = threadIdx.x;
  const int ksb = blockIdx.x;          // 0..5
  const int g0 = blockIdx.y * 256;
  const int kb = ksb * KSTR;
  const int wave = tid >> 6, lane = tid & 63;
  const int wn = wave * 64;
  const int fr = lane & 15, fo = lane >> 4;

  // stage h strip: 32 x 640 ushorts = 20480 = 10 exact passes of 2048
  #pragma unroll
  for (int p = 0; p < 10; ++p) {
    int f = p * 2048 + tid * 8;
    int row = f / 640, col = f % 640;  // both 8-aligned (640 % 8 == 0)
    *(uint4*)&Hh[row][col] = *(const uint4*)(hh_g + (size_t)row * H + kb + col);
  }
  __syncthreads();

  f32x4 acc[2][4];
  #pragma unroll
  for (int i = 0; i < 2; ++i)
    #pragma unroll
    for (int j = 0; j < 4; ++j) { acc[i][j].x = 0.f; acc[i][j].y = 0.f; acc[i][j].z = 0.f; acc[i][j].w = 0.f; }

  f16x8 whc[4], whn[4];
  #pragma unroll
  for (int ni = 0; ni < 4; ++ni)
    whc[ni] = *(const f16x8*)(Wh_g + (size_t)(g0 + wn + ni * 16 + fr) * K_ + kb + fo * 8);

  #pragma unroll 2
  for (int c = 0; c < KSTR / 32; ++c) {
    if (c + 1 < KSTR / 32) {
      const int kn = kb + (c + 1) * 32 + fo * 8;
      #pragma unroll
      for (int ni = 0; ni < 4; ++ni)
        whn[ni] = *(const f16x8*)(Wh_g + (size_t)(g0 + wn + ni * 16 + fr) * K_ + kn);
    }
    f16x8 ah[2];
    #pragma unroll
    for (int mi = 0; mi < 2; ++mi)
      ah[mi] = *(const f16x8*)&Hh[mi * 16 + fr][c * 32 + fo * 8];
    #pragma unroll
    for (int ni = 0; ni < 4; ++ni)
      #pragma unroll
      for (int mi = 0; mi < 2; ++mi)
        acc[mi][ni] = __builtin_amdgcn_mfma_f32_16x16x32_f16(ah[mi], whc[ni], acc[mi][ni], 0, 0, 0);
    #pragma unroll
    for (int ni = 0; ni < 4; ++ni) whc[ni] = whn[ni];
  }
  #pragma unroll
  for (int mi = 0; mi < 2; ++mi)
    #pragma unroll
    for (int ni = 0; ni < 4; ++ni) {
      int g = g0 + wn + ni * 16 + fr;
      #pragma unroll
      for (int r = 0; r < 4; ++r) {
        int b = mi * 16 + fo * 4 + r;
        part[((size_t)ksb * B_ + b) * G3 + g] = acc[mi][ni][r];
      }
    }
}

// ---------------- kernel 4: reduce partials + gates; writes h fp32 + h fp16 ----------------
__global__ __launch_bounds__(256) void k_gates2(const float* __restrict__ part,
                                                const float* __restrict__ gx_t,
                                                const float* __restrict__ b_hh,
                                                float* __restrict__ h,
                                                unsigned short* __restrict__ h_hi) {
  int v = blockIdx.x * 256 + threadIdx.x;       // 0 .. B_*H/4-1
  int b = v / (H / 4);
  int j = (v - b * (H / 4)) * 4;
  float r[4] = {}, z[4] = {}, n[4] = {};
  for (int ks = 0; ks < KSP; ++ks) {
    const float* base = part + ((size_t)ks * B_ + b) * G3;
    float4 pr = *(const float4*)(base + j);
    float4 pz = *(const float4*)(base + H + j);
    float4 pn = *(const float4*)(base + 2 * H + j);
    r[0] += pr.x; r[1] += pr.y; r[2] += pr.z; r[3] += pr.w;
    z[0] += pz.x; z[1] += pz.y; z[2] += pz.z; z[3] += pz.w;
    n[0] += pn.x; n[1] += pn.y; n[2] += pn.z; n[3] += pn.w;
  }
  float4 bhr = *(const float4*)(b_hh + j);
  float4 bhz = *(const float4*)(b_hh + H + j);
  float4 bhn = *(const float4*)(b_hh + 2 * H + j);
  const float* gxp = gx_t + (size_t)b * G3;
  float4 gxr = *(const float4*)(gxp + j);
  float4 gxz = *(const float4*)(gxp + H + j);
  float4 gxn = *(const float4*)(gxp + 2 * H + j);
  float* hp = h + (size_t)b * H + j;
  float4 hv = *(const float4*)hp;
  float ghr[4] = { r[0] + bhr.x, r[1] + bhr.y, r[2] + bhr.z, r[3] + bhr.w };
  float ghz[4] = { z[0] + bhz.x, z[1] + bhz.y, z[2] + bhz.z, z[3] + bhz.w };
  float ghn[4] = { n[0] + bhn.x, n[1] + bhn.y, n[2] + bhn.z, n[3] + bhn.w };
  float gx_r[4] = { gxr.x, gxr.y, gxr.z, gxr.w };
  float gx_z[4] = { gxz.x, gxz.y, gxz.z, gxz.w };
  float gx_n[4] = { gxn.x, gxn.y, gxn.z, gxn.w };
  float hva[4] = { hv.x, hv.y, hv.z, hv.w };
  float out[4];
  unsigned short uh[4];
  #pragma unroll
  for (int q = 0; q < 4; ++q) {
    float rr = 1.0f / (1.0f + __expf(-(gx_r[q] + ghr[q])));
    float zz = 1.0f / (1.0f + __expf(-(gx_z[q] + ghz[q])));
    float nn = tanhf(gx_n[q] + rr * ghn[q]);
    out[q] = (1.0f - zz) * nn + zz * hva[q];
    union { _Float16 f; unsigned short u; } cv;
    cv.f = (_Float16)out[q];
    uh[q] = cv.u;
  }
  *(float4*)hp = make_float4(out[0], out[1], out[2], out[3]);
  union { uint2 u2; unsigned short s[4]; } ph;
  ph.s[0] = uh[0]; ph.s[1] = uh[1]; ph.s[2] = uh[2]; ph.s[3] = uh[3];
  *(uint2*)(h_hi + (size_t)b * H + j) = ph.u2;
}

// ---------------- fallback fp32 GRU kernels (round-2, proven) ----------------
#define GTF    256
#define KSPF   15
#define KSTRF  256
__global__ __launch_bounds__(256) void k_gh_f32(const float* __restrict__ h,
                                                const float* __restrict__ W_hh,
                                                float* __restrict__ part) {
  __shared__ float hsT[32][36];
  __shared__ float Ws[32][GTF + 4];
  const int tid = threadIdx.x;
  const int ks = blockIdx.x;
  const int g0 = blockIdx.y * GTF;
  const int kb = ks * KSTRF;
  const int tx = tid & 31;
  const int ty = tid >> 5;
  const int hb = tid >> 3;
  const int hk = tid & 7;
  float acc[4][8] = {};
  float4 wv[8], hv;
  #pragma unroll
  for (int l = 0; l < 8; ++l) {
    int f = tid + l * 256;
    int gr = f >> 3, kq = f & 7;
    wv[l] = *(const float4*)(W_hh + (size_t)(g0 + gr) * K_ + kb + kq * 4);
  }
  hv = *(const float4*)(h + (size_t)hb * H + kb + hk * 4);
  for (int c = 0; c < KSTRF / 32; ++c) {
    __syncthreads();
    #pragma unroll
    for (int l = 0; l < 8; ++l) {
      int f = tid + l * 256;
      int gr = f >> 3, kq = f & 7;
      Ws[kq * 4 + 0][gr] = wv[l].x; Ws[kq * 4 + 1][gr] = wv[l].y;
      Ws[kq * 4 + 2][gr] = wv[l].z; Ws[kq * 4 + 3][gr] = wv[l].w;
    }
    hsT[hk * 4 + 0][hb] = hv.x; hsT[hk * 4 + 1][hb] = hv.y;
    hsT[hk * 4 + 2][hb] = hv.z; hsT[hk * 4 + 3][hb] = hv.w;
    __syncthreads();
    if (c + 1 < KSTRF / 32) {
      int kc = kb + (c + 1) * 32;
      #pragma unroll
      for (int l = 0; l < 8; ++l) {
        int f = tid + l * 256;
        int gr = f >> 3, kq = f & 7;
        wv[l] = *(const float4*)(W_hh + (size_t)(g0 + gr) * K_ + kc + kq * 4);
      }
      hv = *(const float4*)(h + (size_t)hb * H + kc + hk * 4);
    }
    #pragma unroll
    for (int kk = 0; kk < 32; ++kk) {
      float h4[4], w8[8];
      *(float4*)&h4[0] = *(const float4*)&hsT[kk][ty * 4];
      *(float4*)&w8[0] = *(const float4*)&Ws[kk][tx * 8];
      *(float4*)&w8[4] = *(const float4*)&Ws[kk][tx * 8 + 4];
      #pragma unroll
      for (int i = 0; i < 4; ++i)
        #pragma unroll
        for (int j = 0; j < 8; ++j)
          acc[i][j] = fmaf(h4[i], w8[j], acc[i][j]);
    }
  }
  #pragma unroll
  for (int i = 0; i < 4; ++i) {
    float* dst = part + ((size_t)ks * B_ + ty * 4 + i) * G3 + g0 + tx * 8;
    *(float4*)dst       = make_float4(acc[i][0], acc[i][1], acc[i][2], acc[i][3]);
    *(float4*)(dst + 4) = make_float4(acc[i][4], acc[i][5], acc[i][6], acc[i][7]);
  }
}

__global__ __launch_bounds__(256) void k_gates_f32(const float* __restrict__ part,
                                                   const float* __restrict__ gx_t,
                                                   const float* __restrict__ b_hh,
                                                   float* __restrict__ h) {
  int v = blockIdx.x * 256 + threadIdx.x;
  int b = v / (H / 4);
  int j = (v - b * (H / 4)) * 4;
  float r[4] = {}, z[4] = {}, n[4] = {};
  for (int ks = 0; ks < KSPF; ++ks) {
    const float* base = part + ((size_t)ks * B_ + b) * G3;
    float4 pr = *(const float4*)(base + j);
    float4 pz = *(const float4*)(base + H + j);
    float4 pn = *(const float4*)(base + 2 * H + j);
    r[0] += pr.x; r[1] += pr.y; r[2] += pr.z; r[3] += pr.w;
    z[0] += pz.x; z[1] += pz.y; z[2] += pz.z; z[3] += pz.w;
    n[0] += pn.x; n[1] += pn.y; n[2] += pn.z; n[3] += pn.w;
  }
  float4 bhr = *(const float4*)(b_hh + j);
  float4 bhz = *(const float4*)(b_hh + H + j);
  float4 bhn = *(const float4*)(b_hh + 2 * H + j);
  const float* gxp = gx_t + (size_t)b * G3;
  float4 gxr = *(const float4*)(gxp + j);
  float4 gxz = *(const float4*)(gxp + H + j);
  float4 gxn = *(const float4*)(gxp + 2 * H + j);
  float* hp = h + (size_t)b * H + j;
  float4 hv = *(const float4*)hp;
  float out[4];
  float ghr[4] = { r[0] + bhr.x, r[1] + bhr.y, r[2] + bhr.z, r[3] + bhr.w };
  float ghz[4] = { z[0] + bhz.x, z[1] + bhz.y, z[2] + bhz.z, z[3] + bhz.w };
  float ghn[4] = { n[0] + bhn.x, n[1] + bhn.y, n[2] + bhn.z, n[3] + bhn.w };
  float gxa[4] = { gxr.x, gxr.y, gxr.z, gxr.w };
  float gza[4] = { gxz.x, gxz.y, gxz.z, gxz.w };
  float gna[4] = { gxn.x, gxn.y, gxn.z, gxn.w };
  float hva[4] = { hv.x, hv.y, hv.z, hv.w };
  #pragma unroll
  for (int q = 0; q < 4; ++q) {
    float rr = 1.0f / (1.0f + __expf(-(gxa[q] + ghr[q])));
    float zz = 1.0f / (1.0f + __expf(-(gza[q] + ghz[q])));
    float nn = tanhf(gna[q] + rr * ghn[q]);
    out[q] = (1.0f - zz) * nn + zz * hva[q];
  }
  *(float4*)hp = make_float4(out[0], out[1], out[2], out[3]);
}

// ---------------- kernel 5: out = relu(h).reshape(B,S,128) @ fc2_w^T + fc2_b ----------------
__global__ __launch_bounds__(64) void k_fc2(const float* __restrict__ h,
                                            const float* __restrict__ fc2_w,
                                            const float* __restrict__ fc2_b,
                                            float* __restrict__ out) {
  int bs = blockIdx.x;                // b*30+s
  int b = bs / S_, s = bs % S_;
  int o = threadIdx.x;                // 0..63
  __shared__ float e[H1];
  const float* hr = h + (size_t)b * H + s * H1;
  e[o]      = fmaxf(hr[o], 0.0f);
  e[o + 64] = fmaxf(hr[o + 64], 0.0f);
  __syncthreads();
  float acc = fc2_b[o];
  const float* w = fc2_w + (size_t)o * H1;
  #pragma unroll 8
  for (int c = 0; c < H1; ++c) acc = fmaf(e[c], w[c], acc);
  out[(size_t)bs * OUTF + o] = acc;
}

// ---------------- host-side launcher ----------------
extern "C" void kernel_launch(void* const* d_in, const int* in_sizes, int n_in,
                              void* d_out, int out_size, void* d_ws, size_t ws_size,
                              hipStream_t stream) {
  const float* x     = (const float*)d_in[0];
  // d_in[1] = adj (unused)
  const float* fc_w  = (const float*)d_in[2];
  const float* fc_b  = (const float*)d_in[3];
  const float* W_ih  = (const float*)d_in[4];
  const float* W_hh  = (const float*)d_in[5];
  const float* b_ih  = (const float*)d_in[6];
  const float* b_hh  = (const float*)d_in[7];
  const float* fc2_w = (const float*)d_in[8];
  const float* fc2_b = (const float*)d_in[9];
  float* out = (float*)d_out;

  char* ws = (char*)d_ws;
  // layout: xi_h 11.8MB (part aliases after gemm; 6x32x11520x4 = 8,847,360 B fits) |
  // gx 70.8MB | wih16 | whh16 | h | h_hi
  unsigned short* xi_h  = (unsigned short*)ws;                      // 11,796,480 B
  float* part           = (float*)ws;                               // alias (8,847,360 B)
  float* gx             = (float*)(ws + 11796480);                  // 70,778,880 B -> end 82,575,360
  unsigned short* wih_h = (unsigned short*)(ws + 82575360);         // 88,473,600 B -> end 171,048,960

  const bool big = ws_size >= 260259840ULL;

  // FC + ReLU -> xi fp16; W_ih -> fp16
  k_fc_relu<<<B_ * T_ * S_, 128, 0, stream>>>(x, fc_w, fc_b, xi_h);
  k_cvt_whh<<<21600, 256, 0, stream>>>(W_ih, wih_h);
  // big GEMM: gx = xi @ W_ih^T + b_ih
  k_gemm_f16<<<(M_ / 128) * (G3 / 128), 256, 0, stream>>>(xi_h, wih_h, b_ih, gx);

  if (big) {
    unsigned short* whh_h = (unsigned short*)(ws + 171048960);      // 88,473,600 B -> end 259,522,560
    float* h              = (float*)(ws + 259522560);               // 491,520 B
    unsigned short* h_hi  = (unsigned short*)(ws + 260014080);      // 245,760 B -> end 260,259,840

    k_zero<<<720, 256, 0, stream>>>(h, 184320);   // zeros h + h_hi (contiguous, 737,280 B)
    k_cvt_whh<<<21600, 256, 0, stream>>>(W_hh, whh_h);

    for (int t = 0; t < T_; ++t) {
      k_gh_direct<<<dim3(KSP, G3 / 256), 256, 0, stream>>>(h_hi, whh_h, part);
      k_gates2<<<B_ * H / 4 / 256, 256, 0, stream>>>(part, gx + (size_t)t * B_ * G3, b_hh, h, h_hi);
    }
    k_fc2<<<B_ * S_, 64, 0, stream>>>(h, fc2_w, fc2_b, out);
  } else {
    // fallback: fp32 GRU (round-2 proven path). part (22.1MB) aliases the dead
    // wih region; h follows it.
    float* partf = (float*)(ws + 82575360);                         // 22,118,400 B
    float* h     = (float*)(ws + 104693760);                        // 491,520 B
    k_zero<<<(B_ * H + 255) / 256, 256, 0, stream>>>(h, B_ * H);
    for (int t = 0; t < T_; ++t) {
      k_gh_f32<<<dim3(KSPF, G3 / GTF), 256, 0, stream>>>(h, W_hh, partf);
      k_gates_f32<<<B_ * H / 4 / 256, 256, 0, stream>>>(partf, gx + (size_t)t * B_ * G3, b_hh, h);
    }
    k_fc2<<<B_ * S_, 64, 0, stream>>>(h, fc2_w, fc2_b, out);
  }
}

// Round 19
// 1613.032 us; speedup vs baseline: 1.1303x; 1.1303x over previous
//
#include <hip/hip_runtime.h>
#include <hip/hip_bf16.h>

// Problem constants
#define B_   32
#define T_   48
#define S_   30
#define INF  16
#define H1   128
#define OUTF 64
#define H    3840     // GRU hidden (= GRU input here)
#define G3   11520    // 3*H
#define K_   3840
#define M_   1536     // B_*T_

typedef _Float16 f16x8 __attribute__((ext_vector_type(8)));  // 8 fp16 (4 VGPR)
typedef __attribute__((ext_vector_type(4))) float f32x4;     // MFMA acc

// async global->LDS, 16B per lane; LDS dest must be wave-uniform (HW adds lane*16)
__device__ inline void gl_lds16(const void* g, void* l) {
  __builtin_amdgcn_global_load_lds((const __attribute__((address_space(1))) void*)g,
                                   (__attribute__((address_space(3))) void*)l, 16, 0, 0);
}

// ---------------- kernel 0: zero floats ----------------
__global__ void k_zero(float* __restrict__ p, int n) {
  int i = blockIdx.x * 256 + threadIdx.x;
  if (i < n) p[i] = 0.0f;
}

// ---------------- kernel: [G3][K] fp32 -> single fp16 (used for W_ih AND W_hh) ----------------
__global__ __launch_bounds__(256) void k_cvt_whh(const float* __restrict__ W,
                                                 unsigned short* __restrict__ Wh) {
  size_t i = ((size_t)blockIdx.x * 256 + threadIdx.x) * 8;
  const float4* p = (const float4*)(W + i);
  float4 f0 = p[0], f1 = p[1];
  union { float4 f4; _Float16 h[8]; } ph;
  ph.h[0] = (_Float16)f0.x; ph.h[1] = (_Float16)f0.y;
  ph.h[2] = (_Float16)f0.z; ph.h[3] = (_Float16)f0.w;
  ph.h[4] = (_Float16)f1.x; ph.h[5] = (_Float16)f1.y;
  ph.h[6] = (_Float16)f1.z; ph.h[7] = (_Float16)f1.w;
  *(float4*)(Wh + i) = ph.f4;
}

// ---------------- kernel 1: FC(16->128)+ReLU -> xi single fp16 [T][B][S*128] ----------------
__global__ __launch_bounds__(128) void k_fc_relu(const float* __restrict__ x,
                                                 const float* __restrict__ fc_w,
                                                 const float* __restrict__ fc_b,
                                                 unsigned short* __restrict__ xi_h) {
  int idx = blockIdx.x;              // (b*T_+t)*S_+s
  int s  = idx % S_;
  int bt = idx / S_;
  int t  = bt % T_;
  int b  = bt / T_;
  int hh = threadIdx.x;              // 0..127
  const float* xr = x + (size_t)idx * INF;
  const float* w  = fc_w + (size_t)hh * INF;
  float acc = fc_b[hh];
  #pragma unroll
  for (int i = 0; i < INF; ++i) acc = fmaf(xr[i], w[i], acc);
  acc = fmaxf(acc, 0.0f);
  union { _Float16 f; unsigned short u; } cv;
  cv.f = (_Float16)acc;
  xi_h[((size_t)t * B_ + b) * H + s * H1 + hh] = cv.u;
}

// ---------------- kernel 2: gx = xi @ W_ih^T + b_ih (m97-structure, proven ~275us) ----------------
__global__ __launch_bounds__(256) void k_gemm_f16(const unsigned short* __restrict__ Ahg,
                                                  const unsigned short* __restrict__ Bwh,
                                                  const float* __restrict__ bias,
                                                  float* __restrict__ C) {
  __shared__ __align__(16) char smem[16640];     // Ah:0  Bh:8192 ; epilogue overlay 16640B
  const int tid = threadIdx.x;
  const int NB = G3 / 128;                       // 90, n-fast linear
  const int n0 = (blockIdx.x % NB) * 128;
  const int m0 = (blockIdx.x / NB) * 128;
  const int wave = tid >> 6, lane = tid & 63;
  const int wm = (wave >> 1) * 64, wn = (wave & 1) * 64;
  const int fr = lane & 15, fo = lane >> 4;      // frag row, k-octet

  f32x4 acc[4][4];
  #pragma unroll
  for (int i = 0; i < 4; ++i)
    #pragma unroll
    for (int j = 0; j < 4; ++j) { acc[i][j].x = 0.f; acc[i][j].y = 0.f; acc[i][j].z = 0.f; acc[i][j].w = 0.f; }

  for (int k0 = 0; k0 < K_; k0 += 32) {
    __syncthreads();                             // prev compute done before overwrite
    #pragma unroll
    for (int q = 0; q < 2; ++q) {
      const int i = wave * 2 + q;                // 0..7, wave-uniform
      const int idx = i * 64 + lane;             // 0..511
      const int row = idx >> 2, oct = idx & 3;   // 4 lanes/row: 64B coalesced
      const size_t ga = (size_t)(m0 + row) * K_ + k0 + oct * 8;
      const size_t gb = (size_t)(n0 + row) * K_ + k0 + oct * 8;
      gl_lds16(Ahg + ga, smem + i * 1024);
      gl_lds16(Bwh + gb, smem + 8192 + i * 1024);
    }
    __syncthreads();                             // vmcnt(0) drain -> tiles ready
    f16x8 ah[4];
    #pragma unroll
    for (int mi = 0; mi < 4; ++mi)
      ah[mi] = *(const f16x8*)(smem + (wm + mi * 16 + fr) * 64 + fo * 16);
    #pragma unroll
    for (int ni = 0; ni < 4; ++ni) {
      f16x8 bh = *(const f16x8*)(smem + 8192 + (wn + ni * 16 + fr) * 64 + fo * 16);
      #pragma unroll
      for (int mi = 0; mi < 4; ++mi)
        acc[mi][ni] = __builtin_amdgcn_mfma_f32_16x16x32_f16(ah[mi], bh, acc[mi][ni], 0, 0, 0);
    }
  }
  // epilogue: per-wave LDS transpose -> 256B-contiguous float4 rows (round-1 pattern)
  __syncthreads();                               // all waves done with staged tiles
  float* ep = (float*)(smem) + wave * (16 * 65); // 4160 B/wave, 16640 B total
  #pragma unroll
  for (int mi = 0; mi < 4; ++mi) {
    #pragma unroll
    for (int ni = 0; ni < 4; ++ni) {
      float bc = bias[n0 + wn + ni * 16 + fr];
      #pragma unroll
      for (int r = 0; r < 4; ++r)
        ep[(fo * 4 + r) * 65 + ni * 16 + fr] = acc[mi][ni][r] + bc;
    }
    #pragma unroll
    for (int rr = 0; rr < 4; ++rr) {             // in-wave lgkmcnt ordering suffices
      int lr = rr * 4 + (lane >> 4);             // 0..15
      int lc = (lane & 15) * 4;                  // 0..60
      float4 v = *(float4*)&ep[lr * 65 + lc];
      int row = m0 + wm + mi * 16 + lr;
      *(float4*)(C + (size_t)row * G3 + n0 + wn + lc) = v;   // 16 lanes = 256B/row
    }
  }
}

// ---------------- kernel 3: partial gh via MFMA, single-fp16 h (round-17 proven) ----------------
// KSP=8 is the measured optimum (15: partial traffic dominates; 6: concurrency starves).
#define KSP  8
#define KSTR 480
__global__ __launch_bounds__(256, 4) void k_gh_direct(const unsigned short* __restrict__ hh_g,
                                                      const unsigned short* __restrict__ Wh_g,
                                                      float* __restrict__ part) {
  __shared__ unsigned short Hh[32][488];
  const int tid = threadIdx.x;
  const int ksb = blockIdx.x;          // 0..7
  const int g0 = blockIdx.y * 256;
  const int kb = ksb * KSTR;
  const int wave = tid >> 6, lane = tid & 63;
  const int wn = wave * 64;
  const int fr = lane & 15, fo = lane >> 4;

  // stage h strip: 32 x 480 ushorts = 15360; 8 passes of 2048 (7.5 used)
  #pragma unroll
  for (int p = 0; p < 8; ++p) {
    int f = p * 2048 + tid * 8;
    if (f < 32 * 480) {
      int row = f / 480, col = f % 480;
      *(uint4*)&Hh[row][col] = *(const uint4*)(hh_g + (size_t)row * H + kb + col);
    }
  }
  __syncthreads();

  f32x4 acc[2][4];
  #pragma unroll
  for (int i = 0; i < 2; ++i)
    #pragma unroll
    for (int j = 0; j < 4; ++j) { acc[i][j].x = 0.f; acc[i][j].y = 0.f; acc[i][j].z = 0.f; acc[i][j].w = 0.f; }

  f16x8 whc[4], whn[4];
  #pragma unroll
  for (int ni = 0; ni < 4; ++ni)
    whc[ni] = *(const f16x8*)(Wh_g + (size_t)(g0 + wn + ni * 16 + fr) * K_ + kb + fo * 8);

  #pragma unroll 3
  for (int c = 0; c < KSTR / 32; ++c) {
    if (c + 1 < KSTR / 32) {
      const int kn = kb + (c + 1) * 32 + fo * 8;
      #pragma unroll
      for (int ni = 0; ni < 4; ++ni)
        whn[ni] = *(const f16x8*)(Wh_g + (size_t)(g0 + wn + ni * 16 + fr) * K_ + kn);
    }
    f16x8 ah[2];
    #pragma unroll
    for (int mi = 0; mi < 2; ++mi)
      ah[mi] = *(const f16x8*)&Hh[mi * 16 + fr][c * 32 + fo * 8];
    #pragma unroll
    for (int ni = 0; ni < 4; ++ni)
      #pragma unroll
      for (int mi = 0; mi < 2; ++mi)
        acc[mi][ni] = __builtin_amdgcn_mfma_f32_16x16x32_f16(ah[mi], whc[ni], acc[mi][ni], 0, 0, 0);
    #pragma unroll
    for (int ni = 0; ni < 4; ++ni) whc[ni] = whn[ni];
  }
  #pragma unroll
  for (int mi = 0; mi < 2; ++mi)
    #pragma unroll
    for (int ni = 0; ni < 4; ++ni) {
      int g = g0 + wn + ni * 16 + fr;
      #pragma unroll
      for (int r = 0; r < 4; ++r) {
        int b = mi * 16 + fo * 4 + r;
        part[((size_t)ksb * B_ + b) * G3 + g] = acc[mi][ni][r];
      }
    }
}

// ---------------- kernel 4: reduce partials + gates; writes h fp32 + h fp16 ----------------
__global__ __launch_bounds__(256) void k_gates2(const float* __restrict__ part,
                                                const float* __restrict__ gx_t,
                                                const float* __restrict__ b_hh,
                                                float* __restrict__ h,
                                                unsigned short* __restrict__ h_hi) {
  int v = blockIdx.x * 256 + threadIdx.x;       // 0 .. B_*H/4-1
  int b = v / (H / 4);
  int j = (v - b * (H / 4)) * 4;
  float r[4] = {}, z[4] = {}, n[4] = {};
  for (int ks = 0; ks < KSP; ++ks) {
    const float* base = part + ((size_t)ks * B_ + b) * G3;
    float4 pr = *(const float4*)(base + j);
    float4 pz = *(const float4*)(base + H + j);
    float4 pn = *(const float4*)(base + 2 * H + j);
    r[0] += pr.x; r[1] += pr.y; r[2] += pr.z; r[3] += pr.w;
    z[0] += pz.x; z[1] += pz.y; z[2] += pz.z; z[3] += pz.w;
    n[0] += pn.x; n[1] += pn.y; n[2] += pn.z; n[3] += pn.w;
  }
  float4 bhr = *(const float4*)(b_hh + j);
  float4 bhz = *(const float4*)(b_hh + H + j);
  float4 bhn = *(const float4*)(b_hh + 2 * H + j);
  const float* gxp = gx_t + (size_t)b * G3;
  float4 gxr = *(const float4*)(gxp + j);
  float4 gxz = *(const float4*)(gxp + H + j);
  float4 gxn = *(const float4*)(gxp + 2 * H + j);
  float* hp = h + (size_t)b * H + j;
  float4 hv = *(const float4*)hp;
  float ghr[4] = { r[0] + bhr.x, r[1] + bhr.y, r[2] + bhr.z, r[3] + bhr.w };
  float ghz[4] = { z[0] + bhz.x, z[1] + bhz.y, z[2] + bhz.z, z[3] + bhz.w };
  float ghn[4] = { n[0] + bhn.x, n[1] + bhn.y, n[2] + bhn.z, n[3] + bhn.w };
  float gx_r[4] = { gxr.x, gxr.y, gxr.z, gxr.w };
  float gx_z[4] = { gxz.x, gxz.y, gxz.z, gxz.w };
  float gx_n[4] = { gxn.x, gxn.y, gxn.z, gxn.w };
  float hva[4] = { hv.x, hv.y, hv.z, hv.w };
  float out[4];
  unsigned short uh[4];
  #pragma unroll
  for (int q = 0; q < 4; ++q) {
    float rr = 1.0f / (1.0f + __expf(-(gx_r[q] + ghr[q])));
    float zz = 1.0f / (1.0f + __expf(-(gx_z[q] + ghz[q])));
    float nn = tanhf(gx_n[q] + rr * ghn[q]);
    out[q] = (1.0f - zz) * nn + zz * hva[q];
    union { _Float16 f; unsigned short u; } cv;
    cv.f = (_Float16)out[q];
    uh[q] = cv.u;
  }
  *(float4*)hp = make_float4(out[0], out[1], out[2], out[3]);
  union { uint2 u2; unsigned short s[4]; } ph;
  ph.s[0] = uh[0]; ph.s[1] = uh[1]; ph.s[2] = uh[2]; ph.s[3] = uh[3];
  *(uint2*)(h_hi + (size_t)b * H + j) = ph.u2;
}

// ---------------- fallback fp32 GRU kernels (round-2, proven) ----------------
#define GTF    256
#define KSPF   15
#define KSTRF  256
__global__ __launch_bounds__(256) void k_gh_f32(const float* __restrict__ h,
                                                const float* __restrict__ W_hh,
                                                float* __restrict__ part) {
  __shared__ float hsT[32][36];
  __shared__ float Ws[32][GTF + 4];
  const int tid = threadIdx.x;
  const int ks = blockIdx.x;
  const int g0 = blockIdx.y * GTF;
  const int kb = ks * KSTRF;
  const int tx = tid & 31;
  const int ty = tid >> 5;
  const int hb = tid >> 3;
  const int hk = tid & 7;
  float acc[4][8] = {};
  float4 wv[8], hv;
  #pragma unroll
  for (int l = 0; l < 8; ++l) {
    int f = tid + l * 256;
    int gr = f >> 3, kq = f & 7;
    wv[l] = *(const float4*)(W_hh + (size_t)(g0 + gr) * K_ + kb + kq * 4);
  }
  hv = *(const float4*)(h + (size_t)hb * H + kb + hk * 4);
  for (int c = 0; c < KSTRF / 32; ++c) {
    __syncthreads();
    #pragma unroll
    for (int l = 0; l < 8; ++l) {
      int f = tid + l * 256;
      int gr = f >> 3, kq = f & 7;
      Ws[kq * 4 + 0][gr] = wv[l].x; Ws[kq * 4 + 1][gr] = wv[l].y;
      Ws[kq * 4 + 2][gr] = wv[l].z; Ws[kq * 4 + 3][gr] = wv[l].w;
    }
    hsT[hk * 4 + 0][hb] = hv.x; hsT[hk * 4 + 1][hb] = hv.y;
    hsT[hk * 4 + 2][hb] = hv.z; hsT[hk * 4 + 3][hb] = hv.w;
    __syncthreads();
    if (c + 1 < KSTRF / 32) {
      int kc = kb + (c + 1) * 32;
      #pragma unroll
      for (int l = 0; l < 8; ++l) {
        int f = tid + l * 256;
        int gr = f >> 3, kq = f & 7;
        wv[l] = *(const float4*)(W_hh + (size_t)(g0 + gr) * K_ + kc + kq * 4);
      }
      hv = *(const float4*)(h + (size_t)hb * H + kc + hk * 4);
    }
    #pragma unroll
    for (int kk = 0; kk < 32; ++kk) {
      float h4[4], w8[8];
      *(float4*)&h4[0] = *(const float4*)&hsT[kk][ty * 4];
      *(float4*)&w8[0] = *(const float4*)&Ws[kk][tx * 8];
      *(float4*)&w8[4] = *(const float4*)&Ws[kk][tx * 8 + 4];
      #pragma unroll
      for (int i = 0; i < 4; ++i)
        #pragma unroll
        for (int j = 0; j < 8; ++j)
          acc[i][j] = fmaf(h4[i], w8[j], acc[i][j]);
    }
  }
  #pragma unroll
  for (int i = 0; i < 4; ++i) {
    float* dst = part + ((size_t)ks * B_ + ty * 4 + i) * G3 + g0 + tx * 8;
    *(float4*)dst       = make_float4(acc[i][0], acc[i][1], acc[i][2], acc[i][3]);
    *(float4*)(dst + 4) = make_float4(acc[i][4], acc[i][5], acc[i][6], acc[i][7]);
  }
}

__global__ __launch_bounds__(256) void k_gates_f32(const float* __restrict__ part,
                                                   const float* __restrict__ gx_t,
                                                   const float* __restrict__ b_hh,
                                                   float* __restrict__ h) {
  int v = blockIdx.x * 256 + threadIdx.x;
  int b = v / (H / 4);
  int j = (v - b * (H / 4)) * 4;
  float r[4] = {}, z[4] = {}, n[4] = {};
  for (int ks = 0; ks < KSPF; ++ks) {
    const float* base = part + ((size_t)ks * B_ + b) * G3;
    float4 pr = *(const float4*)(base + j);
    float4 pz = *(const float4*)(base + H + j);
    float4 pn = *(const float4*)(base + 2 * H + j);
    r[0] += pr.x; r[1] += pr.y; r[2] += pr.z; r[3] += pr.w;
    z[0] += pz.x; z[1] += pz.y; z[2] += pz.z; z[3] += pz.w;
    n[0] += pn.x; n[1] += pn.y; n[2] += pn.z; n[3] += pn.w;
  }
  float4 bhr = *(const float4*)(b_hh + j);
  float4 bhz = *(const float4*)(b_hh + H + j);
  float4 bhn = *(const float4*)(b_hh + 2 * H + j);
  const float* gxp = gx_t + (size_t)b * G3;
  float4 gxr = *(const float4*)(gxp + j);
  float4 gxz = *(const float4*)(gxp + H + j);
  float4 gxn = *(const float4*)(gxp + 2 * H + j);
  float* hp = h + (size_t)b * H + j;
  float4 hv = *(const float4*)hp;
  float out[4];
  float ghr[4] = { r[0] + bhr.x, r[1] + bhr.y, r[2] + bhr.z, r[3] + bhr.w };
  float ghz[4] = { z[0] + bhz.x, z[1] + bhz.y, z[2] + bhz.z, z[3] + bhz.w };
  float ghn[4] = { n[0] + bhn.x, n[1] + bhn.y, n[2] + bhn.z, n[3] + bhn.w };
  float gxa[4] = { gxr.x, gxr.y, gxr.z, gxr.w };
  float gza[4] = { gxz.x, gxz.y, gxz.z, gxz.w };
  float gna[4] = { gxn.x, gxn.y, gxn.z, gxn.w };
  float hva[4] = { hv.x, hv.y, hv.z, hv.w };
  #pragma unroll
  for (int q = 0; q < 4; ++q) {
    float rr = 1.0f / (1.0f + __expf(-(gxa[q] + ghr[q])));
    float zz = 1.0f / (1.0f + __expf(-(gza[q] + ghz[q])));
    float nn = tanhf(gna[q] + rr * ghn[q]);
    out[q] = (1.0f - zz) * nn + zz * hva[q];
  }
  *(float4*)hp = make_float4(out[0], out[1], out[2], out[3]);
}

// ---------------- kernel 5: out = relu(h).reshape(B,S,128) @ fc2_w^T + fc2_b ----------------
__global__ __launch_bounds__(64) void k_fc2(const float* __restrict__ h,
                                            const float* __restrict__ fc2_w,
                                            const float* __restrict__ fc2_b,
                                            float* __restrict__ out) {
  int bs = blockIdx.x;                // b*30+s
  int b = bs / S_, s = bs % S_;
  int o = threadIdx.x;                // 0..63
  __shared__ float e[H1];
  const float* hr = h + (size_t)b * H + s * H1;
  e[o]      = fmaxf(hr[o], 0.0f);
  e[o + 64] = fmaxf(hr[o + 64], 0.0f);
  __syncthreads();
  float acc = fc2_b[o];
  const float* w = fc2_w + (size_t)o * H1;
  #pragma unroll 8
  for (int c = 0; c < H1; ++c) acc = fmaf(e[c], w[c], acc);
  out[(size_t)bs * OUTF + o] = acc;
}

// ---------------- host-side launcher ----------------
extern "C" void kernel_launch(void* const* d_in, const int* in_sizes, int n_in,
                              void* d_out, int out_size, void* d_ws, size_t ws_size,
                              hipStream_t stream) {
  const float* x     = (const float*)d_in[0];
  // d_in[1] = adj (unused)
  const float* fc_w  = (const float*)d_in[2];
  const float* fc_b  = (const float*)d_in[3];
  const float* W_ih  = (const float*)d_in[4];
  const float* W_hh  = (const float*)d_in[5];
  const float* b_ih  = (const float*)d_in[6];
  const float* b_hh  = (const float*)d_in[7];
  const float* fc2_w = (const float*)d_in[8];
  const float* fc2_b = (const float*)d_in[9];
  float* out = (float*)d_out;

  char* ws = (char*)d_ws;
  // layout: xi_h 11.8MB (part aliases after gemm) | gx 70.8MB | wih16 | whh16 | h | h_hi
  unsigned short* xi_h  = (unsigned short*)ws;                      // 11,796,480 B
  float* part           = (float*)ws;                               // alias (exactly 11,796,480 B)
  float* gx             = (float*)(ws + 11796480);                  // 70,778,880 B -> end 82,575,360
  unsigned short* wih_h = (unsigned short*)(ws + 82575360);         // 88,473,600 B -> end 171,048,960

  const bool big = ws_size >= 260259840ULL;

  // FC + ReLU -> xi fp16; W_ih -> fp16
  k_fc_relu<<<B_ * T_ * S_, 128, 0, stream>>>(x, fc_w, fc_b, xi_h);
  k_cvt_whh<<<21600, 256, 0, stream>>>(W_ih, wih_h);
  // big GEMM: gx = xi @ W_ih^T + b_ih
  k_gemm_f16<<<(M_ / 128) * (G3 / 128), 256, 0, stream>>>(xi_h, wih_h, b_ih, gx);

  if (big) {
    unsigned short* whh_h = (unsigned short*)(ws + 171048960);      // 88,473,600 B -> end 259,522,560
    float* h              = (float*)(ws + 259522560);               // 491,520 B
    unsigned short* h_hi  = (unsigned short*)(ws + 260014080);      // 245,760 B -> end 260,259,840

    k_zero<<<720, 256, 0, stream>>>(h, 184320);   // zeros h + h_hi (contiguous, 737,280 B)
    k_cvt_whh<<<21600, 256, 0, stream>>>(W_hh, whh_h);

    for (int t = 0; t < T_; ++t) {
      k_gh_direct<<<dim3(KSP, G3 / 256), 256, 0, stream>>>(h_hi, whh_h, part);
      k_gates2<<<B_ * H / 4 / 256, 256, 0, stream>>>(part, gx + (size_t)t * B_ * G3, b_hh, h, h_hi);
    }
    k_fc2<<<B_ * S_, 64, 0, stream>>>(h, fc2_w, fc2_b, out);
  } else {
    // fallback: fp32 GRU (round-2 proven path). part (22.1MB) aliases the dead
    // wih region; h follows it.
    float* partf = (float*)(ws + 82575360);                         // 22,118,400 B
    float* h     = (float*)(ws + 104693760);                        // 491,520 B
    k_zero<<<(B_ * H + 255) / 256, 256, 0, stream>>>(h, B_ * H);
    for (int t = 0; t < T_; ++t) {
      k_gh_f32<<<dim3(KSPF, G3 / GTF), 256, 0, stream>>>(h, W_hh, partf);
      k_gates_f32<<<B_ * H / 4 / 256, 256, 0, stream>>>(partf, gx + (size_t)t * B_ * G3, b_hh, h);
    }
    k_fc2<<<B_ * S_, 64, 0, stream>>>(h, fc2_w, fc2_b, out);
  }
}